// Round 3
// baseline (4693.808 us; speedup 1.0000x reference)
//
#include <hip/hip_runtime.h>

#define TT 2048     // tokens
#define HD 2048     // hidden dim
#define FD 1408     // expert intermediate
#define NE 16       // routed experts
#define NG 18       // routed + 2 shared pseudo-experts

typedef __attribute__((ext_vector_type(4))) float f32x4;
typedef __attribute__((ext_vector_type(8))) short short8;
typedef __attribute__((ext_vector_type(8))) __bf16 bf16x8;
typedef __attribute__((ext_vector_type(4))) unsigned short u16x4;
typedef __attribute__((ext_vector_type(8))) unsigned short u16x8;

__device__ __forceinline__ unsigned short f2bf(float f) {
  unsigned u = __builtin_bit_cast(unsigned, f);
  u += 0x7fffu + ((u >> 16) & 1u);   // RNE
  return (unsigned short)(u >> 16);
}
__device__ __forceinline__ unsigned pack2(float lo, float hi) {
  return (unsigned)f2bf(lo) | ((unsigned)f2bf(hi) << 16);
}

template <typename T>
__device__ __forceinline__ auto mfma_try(T a, T b, f32x4 c, int)
    -> decltype(__builtin_amdgcn_mfma_f32_16x16x32_bf16(a, b, c, 0, 0, 0)) {
  return __builtin_amdgcn_mfma_f32_16x16x32_bf16(a, b, c, 0, 0, 0);
}
template <typename T, typename BV = bf16x8>
__device__ __forceinline__ f32x4 mfma_try(T a, T b, f32x4 c, long) {
  BV aa = __builtin_bit_cast(BV, a);
  BV bb = __builtin_bit_cast(BV, b);
  return __builtin_amdgcn_mfma_f32_16x16x32_bf16(aa, bb, c, 0, 0, 0);
}
__device__ __forceinline__ f32x4 mfma16(short8 a, short8 b, f32x4 c) {
  return mfma_try(a, b, c, 0);
}

// ---------------- gate: logits -> softmax -> top4 -> dense weights ----------
__global__ void gate_kernel(const float* __restrict__ x, const float* __restrict__ gw,
                            float* __restrict__ dense_w) {
  int wid = threadIdx.x >> 6;
  int lane = threadIdx.x & 63;
  int t = blockIdx.x * 4 + wid;
  if (t >= TT) return;
  const float* xr = x + (size_t)t * HD;
  float acc[NE];
#pragma unroll
  for (int e = 0; e < NE; ++e) acc[e] = 0.f;
  for (int h = lane; h < HD; h += 64) {
    float xv = xr[h];
#pragma unroll
    for (int e = 0; e < NE; ++e) acc[e] += xv * gw[e * HD + h];
  }
#pragma unroll
  for (int e = 0; e < NE; ++e) {
    float v = acc[e];
#pragma unroll
    for (int s = 32; s > 0; s >>= 1) v += __shfl_xor(v, s, 64);
    acc[e] = v;
  }
  float mx = acc[0];
#pragma unroll
  for (int e = 1; e < NE; ++e) mx = fmaxf(mx, acc[e]);
  float p[NE]; float sum = 0.f;
#pragma unroll
  for (int e = 0; e < NE; ++e) { p[e] = __expf(acc[e] - mx); sum += p[e]; }
  float inv = 1.f / sum;
#pragma unroll
  for (int e = 0; e < NE; ++e) p[e] *= inv;
  unsigned chosen = 0;
#pragma unroll
  for (int k = 0; k < 4; ++k) {
    int bi = 0; float bv = -1.f;
#pragma unroll
    for (int e = 0; e < NE; ++e) {
      bool ok = !((chosen >> e) & 1) && (p[e] > bv);
      bv = ok ? p[e] : bv;
      bi = ok ? e : bi;
    }
    chosen |= 1u << bi;
  }
  if (lane < NE)
    dense_w[t * NE + lane] = ((chosen >> lane) & 1) ? p[lane] : 0.f;
}

// ---------------- stable per-group token lists ------------------------------
__global__ void build_lists(const float* __restrict__ dense_w, int* __restrict__ tok,
                            float* __restrict__ scale, int* __restrict__ counts) {
  int g = blockIdx.x;
  int lane = threadIdx.x;  // blockDim = 64
  if (g >= NE) {
    for (int i = lane; i < TT; i += 64) { tok[g * TT + i] = i; scale[g * TT + i] = 1.f; }
    if (lane == 0) counts[g] = TT;
    return;
  }
  int base = 0;
  for (int c0 = 0; c0 < TT; c0 += 64) {
    int t = c0 + lane;
    float w = dense_w[t * NE + g];
    bool pred = w > 0.f;
    unsigned long long b = __ballot(pred);
    if (pred) {
      int pos = base + __popcll(b & ((1ull << lane) - 1ull));
      tok[g * TT + pos] = t;
      scale[g * TT + pos] = w;
    }
    base += __popcll(b);
  }
  if (lane == 0) counts[g] = base;
}

__global__ void prefix_kernel(const int* __restrict__ counts, int* __restrict__ rowOff) {
  if (threadIdx.x == 0) {
    int s = 0;
    for (int g = 0; g < NE; ++g) { rowOff[g] = s; s += counts[g]; }
    rowOff[16] = 4 * TT;
    rowOff[17] = 4 * TT + TT;
  }
}

// ---------------- prep: x fp32 -> bf16 --------------------------------------
__global__ void cvt_bf16_kernel(const float* __restrict__ in,
                                unsigned short* __restrict__ out, int n4) {
  int i = blockIdx.x * blockDim.x + threadIdx.x;
  if (i < n4) {
    f32x4 v = ((const f32x4*)in)[i];
    u16x4 h;
    h.x = f2bf(v.x); h.y = f2bf(v.y); h.z = f2bf(v.z); h.w = f2bf(v.w);
    ((u16x4*)out)[i] = h;
  }
}

// ============================================================================
// grouped GEMM 1: Abuf = silu(x Wg) * (x Wu) * w    (BM=128 BN=64 BK=32)
// B staged directly from native fp32 [K][N]; depth-2 reg pipeline on B.
// ============================================================================
__global__ __launch_bounds__(256, 4) void gemm1_fast(
    const unsigned short* __restrict__ xb,
    const float* __restrict__ w_gate, const float* __restrict__ w_up,
    const float* __restrict__ ws_gate, const float* __restrict__ ws_up,
    const int* __restrict__ tok, const float* __restrict__ scale,
    const int* __restrict__ counts, const int* __restrict__ rowOff,
    unsigned short* __restrict__ Abuf) {
  const int g = blockIdx.z, cb = blockIdx.y, rb = blockIdx.x;
  const int count = counts[g];
  if (rb * 128 >= count) return;

  const float *Bg, *Bu; size_t ldb; int bcol0;
  if (g < NE) {
    size_t o = (size_t)g * HD * FD;
    Bg = w_gate + o; Bu = w_up + o; ldb = FD; bcol0 = cb * 64;
  } else {
    Bg = ws_gate; Bu = ws_up; ldb = 2 * FD; bcol0 = (g - NE) * FD + cb * 64;
  }

  __shared__ __align__(16) unsigned short sA[2][128 * 32];
  __shared__ __align__(16) unsigned int   sG[2][64 * 16];
  __shared__ __align__(16) unsigned int   sU[2][64 * 16];

  const int tid = threadIdx.x, lane = tid & 63, wid = tid >> 6;
  const int wr = (wid >> 1) * 64, wc = (wid & 1) * 32;

  // A staging: row ar, two 16B chunks (2h, 2h+1)
  const int ar = tid >> 1, hh = tid & 1;
  int gi0 = rb * 128 + ar;
  int t0 = (gi0 < count) ? tok[g * TT + gi0] : 0;
  const unsigned short* aptr = xb + (size_t)t0 * HD + hh * 16;
  const int aw0 = ar * 32 + (((2 * hh) ^ ((ar >> 1) & 3)) << 3);
  const int aw1 = ar * 32 + (((2 * hh + 1) ^ ((ar >> 1) & 3)) << 3);

  // B staging: k-pair kp (rows 2kp,2kp+1), 4 cols n0..n0+3
  const int kp = tid >> 4, n0 = (tid & 15) * 4;
  const float* gp = Bg + (size_t)(2 * kp) * ldb + bcol0 + n0;
  const float* up = Bu + (size_t)(2 * kp) * ldb + bcol0 + n0;
  int bwi[4];
#pragma unroll
  for (int j = 0; j < 4; ++j)
    bwi[j] = (n0 + j) * 16 + ((((kp >> 2) ^ (((n0 + j) >> 1) & 3))) << 2) + (kp & 3);

  const f32x4 fz = {0.f, 0.f, 0.f, 0.f};
  f32x4 accg[4][2], accu[4][2];
#pragma unroll
  for (int m = 0; m < 4; ++m)
#pragma unroll
    for (int n = 0; n < 2; ++n) { accg[m][n] = fz; accu[m][n] = fz; }

  u16x8 a0, a1;
  f32x4 g0a, g1a, u0a, u1a;   // set 0
  f32x4 g0b, g1b, u0b, u1b;   // set 1

#define LOADA(k0) { a0 = *(const u16x8*)(aptr + (k0)); a1 = *(const u16x8*)(aptr + (k0) + 8); }
#define STOREA(b) { *(u16x8*)&sA[b][aw0] = a0; *(u16x8*)&sA[b][aw1] = a1; }
#define LOADB(k0, G0, G1, U0, U1) { \
    const float* _g = gp + (size_t)(k0) * ldb; const float* _u = up + (size_t)(k0) * ldb; \
    G0 = *(const f32x4*)_g; G1 = *(const f32x4*)(_g + ldb); \
    U0 = *(const f32x4*)_u; U1 = *(const f32x4*)(_u + ldb); }
#define STOREB(b, G0, G1, U0, U1) { \
    _Pragma("unroll") for (int j = 0; j < 4; ++j) { \
      sG[b][bwi[j]] = pack2(G0[j], G1[j]); \
      sU[b][bwi[j]] = pack2(U0[j], U1[j]); } }

  auto COMPUTE = [&](int b) {
    const int ksel = lane >> 4;
    short8 bg[2], bu[2], av[4];
#pragma unroll
    for (int n = 0; n < 2; ++n) {
      int c = wc + n * 16 + (lane & 15);
      int idx = c * 32 + ((ksel ^ ((c >> 1) & 3)) << 3);
      bg[n] = *(const short8*)((const unsigned short*)sG[b] + idx);
      bu[n] = *(const short8*)((const unsigned short*)sU[b] + idx);
    }
#pragma unroll
    for (int m = 0; m < 4; ++m) {
      int r = wr + m * 16 + (lane & 15);
      av[m] = *(const short8*)&sA[b][r * 32 + ((ksel ^ ((r >> 1) & 3)) << 3)];
    }
#pragma unroll
    for (int m = 0; m < 4; ++m)
#pragma unroll
      for (int n = 0; n < 2; ++n) {
        accg[m][n] = mfma16(av[m], bg[n], accg[m][n]);
        accu[m][n] = mfma16(av[m], bu[n], accu[m][n]);
      }
  };

  const int NK = HD / 32;  // 64 (even)
  LOADB(0, g0a, g1a, u0a, u1a);
  LOADA(0);
  STOREA(0);
  STOREB(0, g0a, g1a, u0a, u1a);
  LOADB(32, g0b, g1b, u0b, u1b);
  __syncthreads();

#pragma unroll 1
  for (int s = 0; s < NK; s += 2) {
    // ---- step s (buf 0) ----
    if (s + 2 < NK) LOADB((s + 2) * 32, g0a, g1a, u0a, u1a);
    LOADA((s + 1) * 32);
    COMPUTE(0);
    STOREA(1);
    STOREB(1, g0b, g1b, u0b, u1b);
    __syncthreads();
    // ---- step s+1 (buf 1) ----
    if (s + 3 < NK) LOADB((s + 3) * 32, g0b, g1b, u0b, u1b);
    if (s + 2 < NK) {
      LOADA((s + 2) * 32);
      COMPUTE(1);
      STOREA(0);
      STOREB(0, g0a, g1a, u0a, u1a);
    } else {
      COMPUTE(1);
    }
    __syncthreads();
  }
#undef LOADA
#undef STOREA
#undef LOADB
#undef STOREB

  const int rowBase = rowOff[g] + rb * 128;
#pragma unroll
  for (int m = 0; m < 4; ++m)
#pragma unroll
    for (int r = 0; r < 4; ++r) {
      int rl = wr + m * 16 + ((lane >> 4) << 2) + r;
      int gi = rb * 128 + rl;
      if (gi < count) {
        float sc = scale[g * TT + gi];
#pragma unroll
        for (int n = 0; n < 2; ++n) {
          int cl = wc + n * 16 + (lane & 15);
          float gv = accg[m][n][r], uv = accu[m][n][r];
          float a = gv / (1.f + __expf(-gv)) * uv * sc;
          Abuf[(size_t)(rowBase + rl) * FD + cb * 64 + cl] = f2bf(a);
        }
      }
    }
}

// ============================================================================
// grouped GEMM 2: out[tok] += Abuf @ Wdown   (BM=128 BN=64 BK=32, NK=44)
// ============================================================================
__global__ __launch_bounds__(256, 4) void gemm2_fast(
    const unsigned short* __restrict__ Abuf,
    const float* __restrict__ w_down, const float* __restrict__ ws_down,
    const int* __restrict__ tok, const int* __restrict__ counts,
    const int* __restrict__ rowOff, float* __restrict__ out) {
  const int g = blockIdx.z, cb = blockIdx.y, rb = blockIdx.x;
  const int count = counts[g];
  if (rb * 128 >= count) return;

  const float* Bd = (g < NE) ? (w_down + (size_t)g * FD * HD)
                             : (ws_down + (size_t)(g - NE) * FD * HD);

  __shared__ __align__(16) unsigned short sA[2][128 * 32];
  __shared__ __align__(16) unsigned int   sB[2][64 * 16];

  const int tid = threadIdx.x, lane = tid & 63, wid = tid >> 6;
  const int wr = (wid >> 1) * 64, wc = (wid & 1) * 32;

  const int rowBase = rowOff[g] + rb * 128;

  const int ar = tid >> 1, hh = tid & 1;
  const unsigned short* aptr = Abuf + (size_t)(rowBase + ar) * FD + hh * 16;
  const int aw0 = ar * 32 + (((2 * hh) ^ ((ar >> 1) & 3)) << 3);
  const int aw1 = ar * 32 + (((2 * hh + 1) ^ ((ar >> 1) & 3)) << 3);

  const int kp = tid >> 4, n0 = (tid & 15) * 4;
  const float* bp = Bd + (size_t)(2 * kp) * HD + cb * 64 + n0;
  int bwi[4];
#pragma unroll
  for (int j = 0; j < 4; ++j)
    bwi[j] = (n0 + j) * 16 + ((((kp >> 2) ^ (((n0 + j) >> 1) & 3))) << 2) + (kp & 3);

  const f32x4 fz = {0.f, 0.f, 0.f, 0.f};
  f32x4 acc[4][2];
#pragma unroll
  for (int m = 0; m < 4; ++m)
#pragma unroll
    for (int n = 0; n < 2; ++n) acc[m][n] = fz;

  u16x8 a0, a1;
  f32x4 b0a, b1a, b0b, b1b;

#define LOADA(k0) { a0 = *(const u16x8*)(aptr + (k0)); a1 = *(const u16x8*)(aptr + (k0) + 8); }
#define STOREA(b) { *(u16x8*)&sA[b][aw0] = a0; *(u16x8*)&sA[b][aw1] = a1; }
#define LOADB(k0, B0, B1) { \
    const float* _b = bp + (size_t)(k0) * HD; \
    B0 = *(const f32x4*)_b; B1 = *(const f32x4*)(_b + HD); }
#define STOREB(b, B0, B1) { \
    _Pragma("unroll") for (int j = 0; j < 4; ++j) sB[b][bwi[j]] = pack2(B0[j], B1[j]); }

  auto COMPUTE = [&](int b) {
    const int ksel = lane >> 4;
    short8 bv[2], av[4];
#pragma unroll
    for (int n = 0; n < 2; ++n) {
      int c = wc + n * 16 + (lane & 15);
      bv[n] = *(const short8*)((const unsigned short*)sB[b] + c * 32 + ((ksel ^ ((c >> 1) & 3)) << 3));
    }
#pragma unroll
    for (int m = 0; m < 4; ++m) {
      int r = wr + m * 16 + (lane & 15);
      av[m] = *(const short8*)&sA[b][r * 32 + ((ksel ^ ((r >> 1) & 3)) << 3)];
    }
#pragma unroll
    for (int m = 0; m < 4; ++m)
#pragma unroll
      for (int n = 0; n < 2; ++n) acc[m][n] = mfma16(av[m], bv[n], acc[m][n]);
  };

  const int NK = FD / 32;  // 44 (even)
  LOADB(0, b0a, b1a);
  LOADA(0);
  STOREA(0);
  STOREB(0, b0a, b1a);
  LOADB(32, b0b, b1b);
  __syncthreads();

#pragma unroll 1
  for (int s = 0; s < NK; s += 2) {
    if (s + 2 < NK) LOADB((s + 2) * 32, b0a, b1a);
    LOADA((s + 1) * 32);
    COMPUTE(0);
    STOREA(1);
    STOREB(1, b0b, b1b);
    __syncthreads();
    if (s + 3 < NK) LOADB((s + 3) * 32, b0b, b1b);
    if (s + 2 < NK) {
      LOADA((s + 2) * 32);
      COMPUTE(1);
      STOREA(0);
      STOREB(0, b0a, b1a);
    } else {
      COMPUTE(1);
    }
    __syncthreads();
  }
#undef LOADA
#undef STOREA
#undef LOADB
#undef STOREB

#pragma unroll
  for (int m = 0; m < 4; ++m)
#pragma unroll
    for (int r = 0; r < 4; ++r) {
      int rl = wr + m * 16 + ((lane >> 4) << 2) + r;
      int gi = rb * 128 + rl;
      if (gi < count) {
        int t = tok[g * TT + gi];
        float* op = out + (size_t)t * HD + cb * 64;
#pragma unroll
        for (int n = 0; n < 2; ++n)
          atomicAdd(op + wc + n * 16 + (lane & 15), acc[m][n][r]);
      }
    }
}

// ---------------------------------------------------------------------------
extern "C" void kernel_launch(void* const* d_in, const int* in_sizes, int n_in,
                              void* d_out, int out_size, void* d_ws, size_t ws_size,
                              hipStream_t stream) {
  const float* x      = (const float*)d_in[0];
  const float* gw     = (const float*)d_in[1];
  const float* w_gate = (const float*)d_in[2];
  const float* w_up   = (const float*)d_in[3];
  const float* w_down = (const float*)d_in[4];
  const float* wsg    = (const float*)d_in[5];
  const float* wsu    = (const float*)d_in[6];
  const float* wsd    = (const float*)d_in[7];
  float* out = (float*)d_out;

  char* ws = (char*)d_ws;
  float* dense_w = (float*)(ws);                       // 128KB
  int*   tok     = (int*)(ws + (140 << 10));           // 144KB
  float* scale   = (float*)(ws + (290 << 10));         // 144KB
  int*   counts  = (int*)(ws + (440 << 10));
  int*   rowOff  = (int*)(ws + (441 << 10));
  unsigned short* xb   = (unsigned short*)(ws + (1ull  << 20));  // 8MB
  unsigned short* Abuf = (unsigned short*)(ws + (16ull << 20));  // 33MB

  hipMemsetAsync(d_out, 0, (size_t)out_size * sizeof(float), stream);
  gate_kernel<<<TT / 4, 256, 0, stream>>>(x, gw, dense_w);
  build_lists<<<NG, 64, 0, stream>>>(dense_w, tok, scale, counts);
  prefix_kernel<<<1, 64, 0, stream>>>(counts, rowOff);
  cvt_bf16_kernel<<<(TT * HD / 4 + 255) / 256, 256, 0, stream>>>(x, xb, TT * HD / 4);

  gemm1_fast<<<dim3(16, FD / 64, NG), 256, 0, stream>>>(
      xb, w_gate, w_up, wsg, wsu, tok, scale, counts, rowOff, Abuf);
  gemm2_fast<<<dim3(16, HD / 64, NG), 256, 0, stream>>>(
      Abuf, w_down, wsd, tok, counts, rowOff, out);
}

// Round 4
// 2486.971 us; speedup vs baseline: 1.8874x; 1.8874x over previous
//
#include <hip/hip_runtime.h>

#define TT 2048     // tokens
#define HD 2048     // hidden dim
#define FD 1408     // expert intermediate
#define NE 16       // routed experts
#define NG 18       // routed + 2 shared pseudo-experts

typedef __attribute__((ext_vector_type(4))) float f32x4;
typedef __attribute__((ext_vector_type(8))) short short8;
typedef __attribute__((ext_vector_type(8))) __bf16 bf16x8;
typedef __attribute__((ext_vector_type(4))) unsigned short u16x4;
typedef __attribute__((ext_vector_type(8))) unsigned short u16x8;

__device__ __forceinline__ unsigned short f2bf(float f) {
  unsigned u = __builtin_bit_cast(unsigned, f);
  u += 0x7fffu + ((u >> 16) & 1u);   // RNE
  return (unsigned short)(u >> 16);
}
__device__ __forceinline__ unsigned pack2(float lo, float hi) {
  return (unsigned)f2bf(lo) | ((unsigned)f2bf(hi) << 16);
}

template <typename T>
__device__ __forceinline__ auto mfma_try(T a, T b, f32x4 c, int)
    -> decltype(__builtin_amdgcn_mfma_f32_16x16x32_bf16(a, b, c, 0, 0, 0)) {
  return __builtin_amdgcn_mfma_f32_16x16x32_bf16(a, b, c, 0, 0, 0);
}
template <typename T, typename BV = bf16x8>
__device__ __forceinline__ f32x4 mfma_try(T a, T b, f32x4 c, long) {
  BV aa = __builtin_bit_cast(BV, a);
  BV bb = __builtin_bit_cast(BV, b);
  return __builtin_amdgcn_mfma_f32_16x16x32_bf16(aa, bb, c, 0, 0, 0);
}
__device__ __forceinline__ f32x4 mfma16(short8 a, short8 b, f32x4 c) {
  return mfma_try(a, b, c, 0);
}

// ---------------- gate: logits -> softmax -> top4 -> dense weights ----------
__global__ void gate_kernel(const float* __restrict__ x, const float* __restrict__ gw,
                            float* __restrict__ dense_w) {
  int wid = threadIdx.x >> 6;
  int lane = threadIdx.x & 63;
  int t = blockIdx.x * 4 + wid;
  if (t >= TT) return;
  const float* xr = x + (size_t)t * HD;
  float acc[NE];
#pragma unroll
  for (int e = 0; e < NE; ++e) acc[e] = 0.f;
  for (int h = lane; h < HD; h += 64) {
    float xv = xr[h];
#pragma unroll
    for (int e = 0; e < NE; ++e) acc[e] += xv * gw[e * HD + h];
  }
#pragma unroll
  for (int e = 0; e < NE; ++e) {
    float v = acc[e];
#pragma unroll
    for (int s = 32; s > 0; s >>= 1) v += __shfl_xor(v, s, 64);
    acc[e] = v;
  }
  float mx = acc[0];
#pragma unroll
  for (int e = 1; e < NE; ++e) mx = fmaxf(mx, acc[e]);
  float p[NE]; float sum = 0.f;
#pragma unroll
  for (int e = 0; e < NE; ++e) { p[e] = __expf(acc[e] - mx); sum += p[e]; }
  float inv = 1.f / sum;
#pragma unroll
  for (int e = 0; e < NE; ++e) p[e] *= inv;
  unsigned chosen = 0;
#pragma unroll
  for (int k = 0; k < 4; ++k) {
    int bi = 0; float bv = -1.f;
#pragma unroll
    for (int e = 0; e < NE; ++e) {
      bool ok = !((chosen >> e) & 1) && (p[e] > bv);
      bv = ok ? p[e] : bv;
      bi = ok ? e : bi;
    }
    chosen |= 1u << bi;
  }
  if (lane < NE)
    dense_w[t * NE + lane] = ((chosen >> lane) & 1) ? p[lane] : 0.f;
}

// ---------------- stable per-group token lists ------------------------------
__global__ void build_lists(const float* __restrict__ dense_w, int* __restrict__ tok,
                            float* __restrict__ scale, int* __restrict__ counts) {
  int g = blockIdx.x;
  int lane = threadIdx.x;  // blockDim = 64
  if (g >= NE) {
    for (int i = lane; i < TT; i += 64) { tok[g * TT + i] = i; scale[g * TT + i] = 1.f; }
    if (lane == 0) counts[g] = TT;
    return;
  }
  int base = 0;
  for (int c0 = 0; c0 < TT; c0 += 64) {
    int t = c0 + lane;
    float w = dense_w[t * NE + g];
    bool pred = w > 0.f;
    unsigned long long b = __ballot(pred);
    if (pred) {
      int pos = base + __popcll(b & ((1ull << lane) - 1ull));
      tok[g * TT + pos] = t;
      scale[g * TT + pos] = w;
    }
    base += __popcll(b);
  }
  if (lane == 0) counts[g] = base;
}

__global__ void prefix_kernel(const int* __restrict__ counts, int* __restrict__ rowOff) {
  if (threadIdx.x == 0) {
    int s = 0;
    for (int g = 0; g < NE; ++g) { rowOff[g] = s; s += counts[g]; }
    rowOff[16] = 4 * TT;
    rowOff[17] = 4 * TT + TT;
  }
}

// ---------------- prep: x fp32 -> bf16 --------------------------------------
__global__ void cvt_bf16_kernel(const float* __restrict__ in,
                                unsigned short* __restrict__ out, int n4) {
  int i = blockIdx.x * blockDim.x + threadIdx.x;
  if (i < n4) {
    f32x4 v = ((const f32x4*)in)[i];
    u16x4 h;
    h.x = f2bf(v.x); h.y = f2bf(v.y); h.z = f2bf(v.z); h.w = f2bf(v.w);
    ((u16x4*)out)[i] = h;
  }
}

// ============================================================================
// grouped GEMM 1: Abuf = silu(x Wg) * (x Wu) * w    (BM=128 BN=64 BK=32)
// 1-D grid with panel->XCD affinity: all rb-blocks of one weight panel run on
// the same XCD so the fp32 panel is fetched from HBM once.
// ============================================================================
#define CB1 22
#define NPAN1 (CB1 * NG)            // 396
#define PG1 ((NPAN1 + 7) / 8)       // 50

__global__ __launch_bounds__(256, 4) void gemm1_fast(
    const unsigned short* __restrict__ xb,
    const float* __restrict__ w_gate, const float* __restrict__ w_up,
    const float* __restrict__ ws_gate, const float* __restrict__ ws_up,
    const int* __restrict__ tok, const float* __restrict__ scale,
    const int* __restrict__ counts, const int* __restrict__ rowOff,
    unsigned short* __restrict__ Abuf) {
  const int b = blockIdx.x;
  const int xcd = b & 7;
  const int s_ = b >> 3;
  const int rb = s_ & 15;
  const int panel = (s_ >> 4) * 8 + xcd;
  if (panel >= NPAN1) return;
  const int g = panel / CB1, cb = panel % CB1;
  const int count = counts[g];
  if (rb * 128 >= count) return;

  const float *Bg, *Bu; size_t ldb; int bcol0;
  if (g < NE) {
    size_t o = (size_t)g * HD * FD;
    Bg = w_gate + o; Bu = w_up + o; ldb = FD; bcol0 = cb * 64;
  } else {
    Bg = ws_gate; Bu = ws_up; ldb = 2 * FD; bcol0 = (g - NE) * FD + cb * 64;
  }

  __shared__ __align__(16) unsigned short sA[2][128 * 32];
  __shared__ __align__(16) unsigned int   sG[2][64 * 16];
  __shared__ __align__(16) unsigned int   sU[2][64 * 16];

  const int tid = threadIdx.x, lane = tid & 63, wid = tid >> 6;
  const int wr = (wid >> 1) * 64, wc = (wid & 1) * 32;

  // A staging: row ar, two 16B chunks (2h, 2h+1)
  const int ar = tid >> 1, hh = tid & 1;
  int gi0 = rb * 128 + ar;
  int t0 = (gi0 < count) ? tok[g * TT + gi0] : 0;
  const unsigned short* aptr = xb + (size_t)t0 * HD + hh * 16;
  const int aw0 = ar * 32 + (((2 * hh) ^ ((ar >> 1) & 3)) << 3);
  const int aw1 = ar * 32 + (((2 * hh + 1) ^ ((ar >> 1) & 3)) << 3);

  // B staging: k-pair kp (rows 2kp,2kp+1), 4 cols n0..n0+3
  const int kp = tid >> 4, n0 = (tid & 15) * 4;
  const float* gp = Bg + (size_t)(2 * kp) * ldb + bcol0 + n0;
  const float* up = Bu + (size_t)(2 * kp) * ldb + bcol0 + n0;
  int bwi[4];
#pragma unroll
  for (int j = 0; j < 4; ++j)
    bwi[j] = (n0 + j) * 16 + (((kp >> 2) ^ (((n0 + j) >> 2) & 3)) << 2) + (kp & 3);

  const f32x4 fz = {0.f, 0.f, 0.f, 0.f};
  f32x4 accg[4][2], accu[4][2];
#pragma unroll
  for (int m = 0; m < 4; ++m)
#pragma unroll
    for (int n = 0; n < 2; ++n) { accg[m][n] = fz; accu[m][n] = fz; }

  u16x8 a0, a1;
  f32x4 g0a, g1a, u0a, u1a;   // set 0
  f32x4 g0b, g1b, u0b, u1b;   // set 1

#define LOADA(k0) { a0 = *(const u16x8*)(aptr + (k0)); a1 = *(const u16x8*)(aptr + (k0) + 8); }
#define STOREA(b) { *(u16x8*)&sA[b][aw0] = a0; *(u16x8*)&sA[b][aw1] = a1; }
#define LOADB(k0, G0, G1, U0, U1) { \
    const float* _g = gp + (size_t)(k0) * ldb; const float* _u = up + (size_t)(k0) * ldb; \
    G0 = *(const f32x4*)_g; G1 = *(const f32x4*)(_g + ldb); \
    U0 = *(const f32x4*)_u; U1 = *(const f32x4*)(_u + ldb); }
#define STOREB(b, G0, G1, U0, U1) { \
    _Pragma("unroll") for (int j = 0; j < 4; ++j) { \
      sG[b][bwi[j]] = pack2(G0[j], G1[j]); \
      sU[b][bwi[j]] = pack2(U0[j], U1[j]); } }

  auto COMPUTE = [&](int b_) {
    const int ksel = lane >> 4;
    short8 bg[2], bu[2], av[4];
#pragma unroll
    for (int n = 0; n < 2; ++n) {
      int c = wc + n * 16 + (lane & 15);
      int idx = c * 32 + ((ksel ^ ((c >> 2) & 3)) << 3);
      bg[n] = *(const short8*)((const unsigned short*)sG[b_] + idx);
      bu[n] = *(const short8*)((const unsigned short*)sU[b_] + idx);
    }
#pragma unroll
    for (int m = 0; m < 4; ++m) {
      int r = wr + m * 16 + (lane & 15);
      av[m] = *(const short8*)&sA[b_][r * 32 + ((ksel ^ ((r >> 1) & 3)) << 3)];
    }
#pragma unroll
    for (int m = 0; m < 4; ++m)
#pragma unroll
      for (int n = 0; n < 2; ++n) {
        accg[m][n] = mfma16(av[m], bg[n], accg[m][n]);
        accu[m][n] = mfma16(av[m], bu[n], accu[m][n]);
      }
  };

  const int NK = HD / 32;  // 64 (even)
  LOADB(0, g0a, g1a, u0a, u1a);
  LOADA(0);
  STOREA(0);
  STOREB(0, g0a, g1a, u0a, u1a);
  LOADB(32, g0b, g1b, u0b, u1b);
  __syncthreads();

#pragma unroll 1
  for (int s = 0; s < NK; s += 2) {
    if (s + 2 < NK) LOADB((s + 2) * 32, g0a, g1a, u0a, u1a);
    LOADA((s + 1) * 32);
    COMPUTE(0);
    STOREA(1);
    STOREB(1, g0b, g1b, u0b, u1b);
    __syncthreads();
    if (s + 3 < NK) LOADB((s + 3) * 32, g0b, g1b, u0b, u1b);
    if (s + 2 < NK) {
      LOADA((s + 2) * 32);
      COMPUTE(1);
      STOREA(0);
      STOREB(0, g0a, g1a, u0a, u1a);
    } else {
      COMPUTE(1);
    }
    __syncthreads();
  }
#undef LOADA
#undef STOREA
#undef LOADB
#undef STOREB

  const int rowBase = rowOff[g] + rb * 128;
#pragma unroll
  for (int m = 0; m < 4; ++m)
#pragma unroll
    for (int r = 0; r < 4; ++r) {
      int rl = wr + m * 16 + ((lane >> 4) << 2) + r;
      int gi = rb * 128 + rl;
      if (gi < count) {
        float sc = scale[g * TT + gi];
#pragma unroll
        for (int n = 0; n < 2; ++n) {
          int cl = wc + n * 16 + (lane & 15);
          float gv = accg[m][n][r], uv = accu[m][n][r];
          float a = gv / (1.f + __expf(-gv)) * uv * sc;
          Abuf[(size_t)(rowBase + rl) * FD + cb * 64 + cl] = f2bf(a);
        }
      }
    }
}

// ============================================================================
// grouped GEMM 2: out[tok] += Abuf @ Wdown   (BM=128 BN=64 BK=32, NK=44)
// ============================================================================
#define CB2 32
#define NPAN2 (CB2 * NG)            // 576
#define PG2 (NPAN2 / 8)             // 72

__global__ __launch_bounds__(256, 4) void gemm2_fast(
    const unsigned short* __restrict__ Abuf,
    const float* __restrict__ w_down, const float* __restrict__ ws_down,
    const int* __restrict__ tok, const int* __restrict__ counts,
    const int* __restrict__ rowOff, float* __restrict__ out) {
  const int b = blockIdx.x;
  const int xcd = b & 7;
  const int s_ = b >> 3;
  const int rb = s_ & 15;
  const int panel = (s_ >> 4) * 8 + xcd;
  if (panel >= NPAN2) return;
  const int g = panel / CB2, cb = panel % CB2;
  const int count = counts[g];
  if (rb * 128 >= count) return;

  const float* Bd = (g < NE) ? (w_down + (size_t)g * FD * HD)
                             : (ws_down + (size_t)(g - NE) * FD * HD);

  __shared__ __align__(16) unsigned short sA[2][128 * 32];
  __shared__ __align__(16) unsigned int   sB[2][64 * 16];

  const int tid = threadIdx.x, lane = tid & 63, wid = tid >> 6;
  const int wr = (wid >> 1) * 64, wc = (wid & 1) * 32;

  const int rowBase = rowOff[g] + rb * 128;

  const int ar = tid >> 1, hh = tid & 1;
  const unsigned short* aptr = Abuf + (size_t)(rowBase + ar) * FD + hh * 16;
  const int aw0 = ar * 32 + (((2 * hh) ^ ((ar >> 1) & 3)) << 3);
  const int aw1 = ar * 32 + (((2 * hh + 1) ^ ((ar >> 1) & 3)) << 3);

  const int kp = tid >> 4, n0 = (tid & 15) * 4;
  const float* bp = Bd + (size_t)(2 * kp) * HD + cb * 64 + n0;
  int bwi[4];
#pragma unroll
  for (int j = 0; j < 4; ++j)
    bwi[j] = (n0 + j) * 16 + (((kp >> 2) ^ (((n0 + j) >> 2) & 3)) << 2) + (kp & 3);

  const f32x4 fz = {0.f, 0.f, 0.f, 0.f};
  f32x4 acc[4][2];
#pragma unroll
  for (int m = 0; m < 4; ++m)
#pragma unroll
    for (int n = 0; n < 2; ++n) acc[m][n] = fz;

  u16x8 a0, a1;
  f32x4 b0a, b1a, b0b, b1b;

#define LOADA(k0) { a0 = *(const u16x8*)(aptr + (k0)); a1 = *(const u16x8*)(aptr + (k0) + 8); }
#define STOREA(b) { *(u16x8*)&sA[b][aw0] = a0; *(u16x8*)&sA[b][aw1] = a1; }
#define LOADB(k0, B0, B1) { \
    const float* _b = bp + (size_t)(k0) * HD; \
    B0 = *(const f32x4*)_b; B1 = *(const f32x4*)(_b + HD); }
#define STOREB(b, B0, B1) { \
    _Pragma("unroll") for (int j = 0; j < 4; ++j) sB[b][bwi[j]] = pack2(B0[j], B1[j]); }

  auto COMPUTE = [&](int b_) {
    const int ksel = lane >> 4;
    short8 bv[2], av[4];
#pragma unroll
    for (int n = 0; n < 2; ++n) {
      int c = wc + n * 16 + (lane & 15);
      bv[n] = *(const short8*)((const unsigned short*)sB[b_] + c * 32 + ((ksel ^ ((c >> 2) & 3)) << 3));
    }
#pragma unroll
    for (int m = 0; m < 4; ++m) {
      int r = wr + m * 16 + (lane & 15);
      av[m] = *(const short8*)&sA[b_][r * 32 + ((ksel ^ ((r >> 1) & 3)) << 3)];
    }
#pragma unroll
    for (int m = 0; m < 4; ++m)
#pragma unroll
      for (int n = 0; n < 2; ++n) acc[m][n] = mfma16(av[m], bv[n], acc[m][n]);
  };

  const int NK = FD / 32;  // 44 (even)
  LOADB(0, b0a, b1a);
  LOADA(0);
  STOREA(0);
  STOREB(0, b0a, b1a);
  LOADB(32, b0b, b1b);
  __syncthreads();

#pragma unroll 1
  for (int s = 0; s < NK; s += 2) {
    if (s + 2 < NK) LOADB((s + 2) * 32, b0a, b1a);
    LOADA((s + 1) * 32);
    COMPUTE(0);
    STOREA(1);
    STOREB(1, b0b, b1b);
    __syncthreads();
    if (s + 3 < NK) LOADB((s + 3) * 32, b0b, b1b);
    if (s + 2 < NK) {
      LOADA((s + 2) * 32);
      COMPUTE(1);
      STOREA(0);
      STOREB(0, b0a, b1a);
    } else {
      COMPUTE(1);
    }
    __syncthreads();
  }
#undef LOADA
#undef STOREA
#undef LOADB
#undef STOREB

#pragma unroll
  for (int m = 0; m < 4; ++m)
#pragma unroll
    for (int r = 0; r < 4; ++r) {
      int rl = wr + m * 16 + ((lane >> 4) << 2) + r;
      int gi = rb * 128 + rl;
      if (gi < count) {
        int t = tok[g * TT + gi];
        float* op = out + (size_t)t * HD + cb * 64;
#pragma unroll
        for (int n = 0; n < 2; ++n)
          atomicAdd(op + wc + n * 16 + (lane & 15), acc[m][n][r]);
      }
    }
}

// ---------------------------------------------------------------------------
extern "C" void kernel_launch(void* const* d_in, const int* in_sizes, int n_in,
                              void* d_out, int out_size, void* d_ws, size_t ws_size,
                              hipStream_t stream) {
  const float* x      = (const float*)d_in[0];
  const float* gw     = (const float*)d_in[1];
  const float* w_gate = (const float*)d_in[2];
  const float* w_up   = (const float*)d_in[3];
  const float* w_down = (const float*)d_in[4];
  const float* wsg    = (const float*)d_in[5];
  const float* wsu    = (const float*)d_in[6];
  const float* wsd    = (const float*)d_in[7];
  float* out = (float*)d_out;

  char* ws = (char*)d_ws;
  float* dense_w = (float*)(ws);                       // 128KB
  int*   tok     = (int*)(ws + (140 << 10));           // 144KB
  float* scale   = (float*)(ws + (290 << 10));         // 144KB
  int*   counts  = (int*)(ws + (440 << 10));
  int*   rowOff  = (int*)(ws + (441 << 10));
  unsigned short* xb   = (unsigned short*)(ws + (1ull  << 20));  // 8MB
  unsigned short* Abuf = (unsigned short*)(ws + (16ull << 20));  // 33MB

  hipMemsetAsync(d_out, 0, (size_t)out_size * sizeof(float), stream);
  gate_kernel<<<TT / 4, 256, 0, stream>>>(x, gw, dense_w);
  build_lists<<<NG, 64, 0, stream>>>(dense_w, tok, scale, counts);
  prefix_kernel<<<1, 64, 0, stream>>>(counts, rowOff);
  cvt_bf16_kernel<<<(TT * HD / 4 + 255) / 256, 256, 0, stream>>>(x, xb, TT * HD / 4);

  gemm1_fast<<<8 * PG1 * 16, 256, 0, stream>>>(
      xb, w_gate, w_up, wsg, wsu, tok, scale, counts, rowOff, Abuf);
  gemm2_fast<<<8 * PG2 * 16, 256, 0, stream>>>(
      Abuf, w_down, wsd, tok, counts, rowOff, out);
}

// Round 5
// 602.652 us; speedup vs baseline: 7.7886x; 4.1267x over previous
//
#include <hip/hip_runtime.h>

#define TT 2048     // tokens
#define HD 2048     // hidden dim
#define FD 1408     // expert intermediate
#define NE 16       // routed experts
#define NG 18       // routed + 2 shared pseudo-experts

typedef __attribute__((ext_vector_type(4))) float f32x4;
typedef __attribute__((ext_vector_type(8))) short short8;
typedef __attribute__((ext_vector_type(8))) __bf16 bf16x8;
typedef __attribute__((ext_vector_type(4))) unsigned short u16x4;
typedef __attribute__((ext_vector_type(8))) unsigned short u16x8;

__device__ __forceinline__ unsigned short f2bf(float f) {
  unsigned u = __builtin_bit_cast(unsigned, f);
  u += 0x7fffu + ((u >> 16) & 1u);   // RNE
  return (unsigned short)(u >> 16);
}

template <typename T>
__device__ __forceinline__ auto mfma_try(T a, T b, f32x4 c, int)
    -> decltype(__builtin_amdgcn_mfma_f32_16x16x32_bf16(a, b, c, 0, 0, 0)) {
  return __builtin_amdgcn_mfma_f32_16x16x32_bf16(a, b, c, 0, 0, 0);
}
template <typename T, typename BV = bf16x8>
__device__ __forceinline__ f32x4 mfma_try(T a, T b, f32x4 c, long) {
  BV aa = __builtin_bit_cast(BV, a);
  BV bb = __builtin_bit_cast(BV, b);
  return __builtin_amdgcn_mfma_f32_16x16x32_bf16(aa, bb, c, 0, 0, 0);
}
__device__ __forceinline__ f32x4 mfma16(short8 a, short8 b, f32x4 c) {
  return mfma_try(a, b, c, 0);
}

// async 16B global->LDS (linear dest: wave base + lane*16)
__device__ __forceinline__ void gload16(const void* g, void* l) {
  __builtin_amdgcn_global_load_lds(
      (const __attribute__((address_space(1))) void*)g,
      (__attribute__((address_space(3))) void*)l, 16, 0, 0);
}

// ---------------- gate: logits -> softmax -> top4 -> dense weights ----------
__global__ void gate_kernel(const float* __restrict__ x, const float* __restrict__ gw,
                            float* __restrict__ dense_w) {
  int wid = threadIdx.x >> 6;
  int lane = threadIdx.x & 63;
  int t = blockIdx.x * 4 + wid;
  if (t >= TT) return;
  const float* xr = x + (size_t)t * HD;
  float acc[NE];
#pragma unroll
  for (int e = 0; e < NE; ++e) acc[e] = 0.f;
  for (int h = lane; h < HD; h += 64) {
    float xv = xr[h];
#pragma unroll
    for (int e = 0; e < NE; ++e) acc[e] += xv * gw[e * HD + h];
  }
#pragma unroll
  for (int e = 0; e < NE; ++e) {
    float v = acc[e];
#pragma unroll
    for (int s = 32; s > 0; s >>= 1) v += __shfl_xor(v, s, 64);
    acc[e] = v;
  }
  float mx = acc[0];
#pragma unroll
  for (int e = 1; e < NE; ++e) mx = fmaxf(mx, acc[e]);
  float p[NE]; float sum = 0.f;
#pragma unroll
  for (int e = 0; e < NE; ++e) { p[e] = __expf(acc[e] - mx); sum += p[e]; }
  float inv = 1.f / sum;
#pragma unroll
  for (int e = 0; e < NE; ++e) p[e] *= inv;
  unsigned chosen = 0;
#pragma unroll
  for (int k = 0; k < 4; ++k) {
    int bi = 0; float bv = -1.f;
#pragma unroll
    for (int e = 0; e < NE; ++e) {
      bool ok = !((chosen >> e) & 1) && (p[e] > bv);
      bv = ok ? p[e] : bv;
      bi = ok ? e : bi;
    }
    chosen |= 1u << bi;
  }
  if (lane < NE)
    dense_w[t * NE + lane] = ((chosen >> lane) & 1) ? p[lane] : 0.f;
}

// ---------------- stable per-group token lists ------------------------------
__global__ void build_lists(const float* __restrict__ dense_w, int* __restrict__ tok,
                            float* __restrict__ scale, int* __restrict__ counts) {
  int g = blockIdx.x;
  int lane = threadIdx.x;  // blockDim = 64
  if (g >= NE) {
    for (int i = lane; i < TT; i += 64) { tok[g * TT + i] = i; scale[g * TT + i] = 1.f; }
    if (lane == 0) counts[g] = TT;
    return;
  }
  int base = 0;
  for (int c0 = 0; c0 < TT; c0 += 64) {
    int t = c0 + lane;
    float w = dense_w[t * NE + g];
    bool pred = w > 0.f;
    unsigned long long b = __ballot(pred);
    if (pred) {
      int pos = base + __popcll(b & ((1ull << lane) - 1ull));
      tok[g * TT + pos] = t;
      scale[g * TT + pos] = w;
    }
    base += __popcll(b);
  }
  if (lane == 0) counts[g] = base;
}

__global__ void prefix_kernel(const int* __restrict__ counts, int* __restrict__ rowOff) {
  if (threadIdx.x == 0) {
    int s = 0;
    for (int g = 0; g < NE; ++g) { rowOff[g] = s; s += counts[g]; }
    rowOff[16] = 4 * TT;
    rowOff[17] = 4 * TT + TT;
  }
}

// ---------------- prep: x fp32 -> bf16 --------------------------------------
__global__ void cvt_bf16_kernel(const float* __restrict__ in,
                                unsigned short* __restrict__ out, int n4) {
  int i = blockIdx.x * blockDim.x + threadIdx.x;
  if (i < n4) {
    f32x4 v = ((const f32x4*)in)[i];
    u16x4 h;
    h.x = f2bf(v.x); h.y = f2bf(v.y); h.z = f2bf(v.z); h.w = f2bf(v.w);
    ((u16x4*)out)[i] = h;
  }
}

// ---------------- prep: fp32 [B][R][C] -> bf16 [B][C][R] tiled transpose ----
__global__ __launch_bounds__(256) void transpose_bf16_kernel(
    const float* __restrict__ in, unsigned short* __restrict__ out, int R, int C) {
  __shared__ float tile[64 * 65];
  const size_t base = (size_t)blockIdx.z * R * C;
  const int c0 = blockIdx.x * 64, r0 = blockIdx.y * 64;
  const int tid = threadIdx.x;
  const int rr = tid >> 4;
  const int c4 = (tid & 15) * 4;
#pragma unroll
  for (int it = 0; it < 4; ++it) {
    int r = rr + it * 16;
    f32x4 v = *(const f32x4*)(in + base + (size_t)(r0 + r) * C + c0 + c4);
#pragma unroll
    for (int i = 0; i < 4; ++i) tile[(c4 + i) * 65 + r] = v[i];
  }
  __syncthreads();
  const int cl = tid >> 3;
  const int rc = (tid & 7) * 8;
#pragma unroll
  for (int it = 0; it < 2; ++it) {
    int c = cl + it * 32;
    u16x8 h;
#pragma unroll
    for (int j = 0; j < 8; ++j) h[j] = f2bf(tile[c * 65 + rc + j]);
    *(u16x8*)(out + base + (size_t)(c0 + c) * R + r0 + rc) = h;
  }
}

// ============================================================================
// grouped GEMM 1: Abuf = silu(x Wg)*(x Wu)*w   BM=128 BN=64 BK=32, gload_lds
// ============================================================================
#define CB1 (FD / 64)               // 22
#define NPAN1 (CB1 * NG)            // 396
#define PG1 ((NPAN1 + 7) / 8)       // 50

__global__ __launch_bounds__(256, 4) void gemm1_v5(
    const unsigned short* __restrict__ xb,
    const unsigned short* __restrict__ wgT, const unsigned short* __restrict__ wuT,
    const unsigned short* __restrict__ wsgT, const unsigned short* __restrict__ wsuT,
    const int* __restrict__ tok, const float* __restrict__ scale,
    const int* __restrict__ counts, const int* __restrict__ rowOff,
    unsigned short* __restrict__ Abuf) {
  const int b = blockIdx.x;
  const int xcd = b & 7;
  const int s_ = b >> 3;
  const int rb = s_ & 15;
  const int panel = (s_ >> 4) * 8 + xcd;
  if (panel >= NPAN1) return;
  const int g = panel / CB1, cb = panel % CB1;
  const int count = counts[g];
  if (rb * 128 >= count) return;

  __shared__ __align__(16) unsigned short sA[2][128 * 32];
  __shared__ __align__(16) unsigned short sG[2][64 * 32];
  __shared__ __align__(16) unsigned short sU[2][64 * 32];

  const int tid = threadIdx.x, lane = tid & 63, wid = tid >> 6;
  const int wr = (wid >> 1) * 64, wc = (wid & 1) * 32;

  // ---- staging addresses (per-lane global, wave-uniform LDS dest) ----
  // A: 8 segs of 16 rows; wave stages segs {2w, 2w+1}. lane: row=16s+(l>>2), chunk=l&3
  const int lr = lane >> 2, lc = lane & 3;
  const int ra0 = wid * 32 + lr, ra1 = wid * 32 + 16 + lr;
  int gi0 = rb * 128 + ra0, gi1 = rb * 128 + ra1;
  int t0 = (gi0 < count) ? tok[g * TT + gi0] : 0;
  int t1 = (gi1 < count) ? tok[g * TT + gi1] : 0;
  const unsigned short* aG0 = xb + (size_t)t0 * HD + ((lc ^ ((ra0 >> 1) & 3)) * 8);
  const unsigned short* aG1 = xb + (size_t)t1 * HD + ((lc ^ ((ra1 >> 1) & 3)) * 8);
  // B: 4 segs of 16 rows(cols-of-output); wave stages seg w for both G and U
  const int rbb = wid * 16 + lr;
  const unsigned short *bGg, *bGu;
  if (g < NE) {
    size_t o = (size_t)g * FD * HD + (size_t)(cb * 64 + rbb) * HD;
    bGg = wgT + o; bGu = wuT + o;
  } else {
    size_t o = (size_t)((g - NE) * FD + cb * 64 + rbb) * HD;
    bGg = wsgT + o; bGu = wsuT + o;
  }
  const int bco = (lc ^ ((rbb >> 1) & 3)) * 8;
  bGg += bco; bGu += bco;

  const f32x4 fz = {0.f, 0.f, 0.f, 0.f};
  f32x4 accg[4][2], accu[4][2];
#pragma unroll
  for (int m = 0; m < 4; ++m)
#pragma unroll
    for (int n = 0; n < 2; ++n) { accg[m][n] = fz; accu[m][n] = fz; }

  auto STAGE = [&](int bu, int s) {
    size_t ko = (size_t)s * 32;
    gload16(aG0 + ko, &sA[bu][wid * 1024 + lr * 32]);        // seg 2w   (lane adds 16B)
    gload16(aG1 + ko, &sA[bu][wid * 1024 + 512 + lr * 32]);  // seg 2w+1
    gload16(bGg + ko, &sG[bu][wid * 512 + lr * 32]);
    gload16(bGu + ko, &sU[bu][wid * 512 + lr * 32]);
  };
  // NOTE: LDS dest must be wave-uniform base; lane offset implicit. Pass seg base:
  auto STAGEW = [&](int bu, int s) {
    size_t ko = (size_t)s * 32;
    gload16(aG0 + ko, &sA[bu][wid * 1024]);
    gload16(aG1 + ko, &sA[bu][wid * 1024 + 512]);
    gload16(bGg + ko, &sG[bu][wid * 512]);
    gload16(bGu + ko, &sU[bu][wid * 512]);
  };
  (void)STAGE;

  auto COMPUTE = [&](int bu) {
    const int ksel = lane >> 4;
    short8 av[4], bg[2], bv[2];
#pragma unroll
    for (int n = 0; n < 2; ++n) {
      int c = wc + n * 16 + (lane & 15);
      int idx = c * 32 + ((ksel ^ ((c >> 1) & 3)) << 3);
      bg[n] = *(const short8*)&sG[bu][idx];
      bv[n] = *(const short8*)&sU[bu][idx];
    }
#pragma unroll
    for (int m = 0; m < 4; ++m) {
      int r = wr + m * 16 + (lane & 15);
      av[m] = *(const short8*)&sA[bu][r * 32 + ((ksel ^ ((r >> 1) & 3)) << 3)];
    }
#pragma unroll
    for (int m = 0; m < 4; ++m)
#pragma unroll
      for (int n = 0; n < 2; ++n) {
        accg[m][n] = mfma16(av[m], bg[n], accg[m][n]);
        accu[m][n] = mfma16(av[m], bv[n], accu[m][n]);
      }
  };

  const int NK = HD / 32;  // 64
  STAGEW(0, 0);
  __syncthreads();
  int bu = 0;
#pragma unroll 1
  for (int s = 0; s < NK; ++s) {
    if (s + 1 < NK) STAGEW(bu ^ 1, s + 1);
    COMPUTE(bu);
    __syncthreads();
    bu ^= 1;
  }

  const int rowBase = rowOff[g] + rb * 128;
#pragma unroll
  for (int m = 0; m < 4; ++m)
#pragma unroll
    for (int r = 0; r < 4; ++r) {
      int rl = wr + m * 16 + ((lane >> 4) << 2) + r;
      int gi = rb * 128 + rl;
      if (gi < count) {
        float sc = scale[g * TT + gi];
#pragma unroll
        for (int n = 0; n < 2; ++n) {
          int cl = wc + n * 16 + (lane & 15);
          float gv = accg[m][n][r], uv = accu[m][n][r];
          float a = gv / (1.f + __expf(-gv)) * uv * sc;
          Abuf[(size_t)(rowBase + rl) * FD + cb * 64 + cl] = f2bf(a);
        }
      }
    }
}

// ============================================================================
// grouped GEMM 2: out[tok] += Abuf @ WdownT   BM=128 BN=128 BK=32, gload_lds
// ============================================================================
#define CB2 (HD / 128)              // 16
#define NPAN2 (CB2 * NG)            // 288
#define PG2 (NPAN2 / 8)             // 36

__global__ __launch_bounds__(256, 4) void gemm2_v5(
    const unsigned short* __restrict__ Abuf,
    const unsigned short* __restrict__ wdT, const unsigned short* __restrict__ wsdT,
    const int* __restrict__ tok, const int* __restrict__ counts,
    const int* __restrict__ rowOff, float* __restrict__ out) {
  const int b = blockIdx.x;
  const int xcd = b & 7;
  const int s_ = b >> 3;
  const int rb = s_ & 15;
  const int panel = (s_ >> 4) * 8 + xcd;
  if (panel >= NPAN2) return;
  const int g = panel / CB2, cb = panel % CB2;
  const int count = counts[g];
  if (rb * 128 >= count) return;

  __shared__ __align__(16) unsigned short sA[2][128 * 32];
  __shared__ __align__(16) unsigned short sB[2][128 * 32];

  const int tid = threadIdx.x, lane = tid & 63, wid = tid >> 6;
  const int wr = (wid >> 1) * 64, wc = (wid & 1) * 64;

  const int rowBase = rowOff[g] + rb * 128;

  const int lr = lane >> 2, lc = lane & 3;
  // A: 8 segs, wave stages {2w,2w+1}
  const int ra0 = wid * 32 + lr, ra1 = wid * 32 + 16 + lr;
  const unsigned short* aG0 =
      Abuf + (size_t)(rowBase + ra0) * FD + ((lc ^ ((ra0 >> 1) & 3)) * 8);
  const unsigned short* aG1 =
      Abuf + (size_t)(rowBase + ra1) * FD + ((lc ^ ((ra1 >> 1) & 3)) * 8);
  // B: 8 segs, wave stages {2w,2w+1}; row = output col h
  const int rb0 = wid * 32 + lr, rb1 = wid * 32 + 16 + lr;
  const unsigned short *bG0, *bG1;
  if (g < NE) {
    bG0 = wdT + (size_t)g * HD * FD + (size_t)(cb * 128 + rb0) * FD;
    bG1 = wdT + (size_t)g * HD * FD + (size_t)(cb * 128 + rb1) * FD;
  } else {
    bG0 = wsdT + (size_t)(cb * 128 + rb0) * (2 * FD) + (size_t)(g - NE) * FD;
    bG1 = wsdT + (size_t)(cb * 128 + rb1) * (2 * FD) + (size_t)(g - NE) * FD;
  }
  bG0 += (lc ^ ((rb0 >> 1) & 3)) * 8;
  bG1 += (lc ^ ((rb1 >> 1) & 3)) * 8;

  const f32x4 fz = {0.f, 0.f, 0.f, 0.f};
  f32x4 acc[4][4];
#pragma unroll
  for (int m = 0; m < 4; ++m)
#pragma unroll
    for (int n = 0; n < 4; ++n) acc[m][n] = fz;

  auto STAGEW = [&](int bu, int s) {
    size_t ko = (size_t)s * 32;
    gload16(aG0 + ko, &sA[bu][wid * 1024]);
    gload16(aG1 + ko, &sA[bu][wid * 1024 + 512]);
    gload16(bG0 + ko, &sB[bu][wid * 1024]);
    gload16(bG1 + ko, &sB[bu][wid * 1024 + 512]);
  };

  auto COMPUTE = [&](int bu) {
    const int ksel = lane >> 4;
    short8 av[4], bv[4];
#pragma unroll
    for (int n = 0; n < 4; ++n) {
      int c = wc + n * 16 + (lane & 15);
      bv[n] = *(const short8*)&sB[bu][c * 32 + ((ksel ^ ((c >> 1) & 3)) << 3)];
    }
#pragma unroll
    for (int m = 0; m < 4; ++m) {
      int r = wr + m * 16 + (lane & 15);
      av[m] = *(const short8*)&sA[bu][r * 32 + ((ksel ^ ((r >> 1) & 3)) << 3)];
    }
#pragma unroll
    for (int m = 0; m < 4; ++m)
#pragma unroll
      for (int n = 0; n < 4; ++n) acc[m][n] = mfma16(av[m], bv[n], acc[m][n]);
  };

  const int NK = FD / 32;  // 44
  STAGEW(0, 0);
  __syncthreads();
  int bu = 0;
#pragma unroll 1
  for (int s = 0; s < NK; ++s) {
    if (s + 1 < NK) STAGEW(bu ^ 1, s + 1);
    COMPUTE(bu);
    __syncthreads();
    bu ^= 1;
  }

#pragma unroll
  for (int m = 0; m < 4; ++m)
#pragma unroll
    for (int r = 0; r < 4; ++r) {
      int rl = wr + m * 16 + ((lane >> 4) << 2) + r;
      int gi = rb * 128 + rl;
      if (gi < count) {
        int t = tok[g * TT + gi];
        float* op = out + (size_t)t * HD + cb * 128;
#pragma unroll
        for (int n = 0; n < 4; ++n)
          atomicAdd(op + wc + n * 16 + (lane & 15), acc[m][n][r]);
      }
    }
}

// ---------------------------------------------------------------------------
extern "C" void kernel_launch(void* const* d_in, const int* in_sizes, int n_in,
                              void* d_out, int out_size, void* d_ws, size_t ws_size,
                              hipStream_t stream) {
  const float* x      = (const float*)d_in[0];
  const float* gw     = (const float*)d_in[1];
  const float* w_gate = (const float*)d_in[2];
  const float* w_up   = (const float*)d_in[3];
  const float* w_down = (const float*)d_in[4];
  const float* wsg    = (const float*)d_in[5];
  const float* wsu    = (const float*)d_in[6];
  const float* wsd    = (const float*)d_in[7];
  float* out = (float*)d_out;

  char* ws = (char*)d_ws;
  float* dense_w = (float*)(ws);                       // 128KB
  int*   tok     = (int*)(ws + (140 << 10));
  float* scale   = (float*)(ws + (290 << 10));
  int*   counts  = (int*)(ws + (440 << 10));
  int*   rowOff  = (int*)(ws + (441 << 10));
  unsigned short* Abuf = (unsigned short*)(ws + (1ull  << 20));   // 34.6MB
  unsigned short* xb   = (unsigned short*)(ws + (36ull << 20));   // 8MB
  unsigned short* wgT  = (unsigned short*)(ws + (44ull  << 20));  // 92.3MB
  unsigned short* wuT  = (unsigned short*)(ws + (137ull << 20));  // 92.3MB
  unsigned short* wdT  = (unsigned short*)(ws + (230ull << 20));  // 92.3MB
  unsigned short* wsgT = (unsigned short*)(ws + (323ull << 20));  // 11.5MB
  unsigned short* wsuT = (unsigned short*)(ws + (335ull << 20));  // 11.5MB
  unsigned short* wsdT = (unsigned short*)(ws + (347ull << 20));  // 11.5MB

  hipMemsetAsync(d_out, 0, (size_t)out_size * sizeof(float), stream);
  gate_kernel<<<TT / 4, 256, 0, stream>>>(x, gw, dense_w);
  build_lists<<<NG, 64, 0, stream>>>(dense_w, tok, scale, counts);
  prefix_kernel<<<1, 64, 0, stream>>>(counts, rowOff);
  cvt_bf16_kernel<<<(TT * HD / 4 + 255) / 256, 256, 0, stream>>>(x, xb, TT * HD / 4);
  transpose_bf16_kernel<<<dim3(FD / 64, HD / 64, NE), 256, 0, stream>>>(w_gate, wgT, HD, FD);
  transpose_bf16_kernel<<<dim3(FD / 64, HD / 64, NE), 256, 0, stream>>>(w_up,   wuT, HD, FD);
  transpose_bf16_kernel<<<dim3(HD / 64, FD / 64, NE), 256, 0, stream>>>(w_down, wdT, FD, HD);
  transpose_bf16_kernel<<<dim3(2 * FD / 64, HD / 64, 1), 256, 0, stream>>>(wsg, wsgT, HD, 2 * FD);
  transpose_bf16_kernel<<<dim3(2 * FD / 64, HD / 64, 1), 256, 0, stream>>>(wsu, wsuT, HD, 2 * FD);
  transpose_bf16_kernel<<<dim3(HD / 64, 2 * FD / 64, 1), 256, 0, stream>>>(wsd, wsdT, 2 * FD, HD);

  gemm1_v5<<<8 * PG1 * 16, 256, 0, stream>>>(
      xb, wgT, wuT, wsgT, wsuT, tok, scale, counts, rowOff, Abuf);
  gemm2_v5<<<8 * PG2 * 16, 256, 0, stream>>>(
      Abuf, wdT, wsdT, tok, counts, rowOff, out);
}